// Round 2
// baseline (302.673 us; speedup 1.0000x reference)
//
#include <hip/hip_runtime.h>
#include <hip/hip_bf16.h>
#include <stdint.h>

// DynamicFc: out = (tiny per-sample MLP with generated weights) + f + pf.
// B=8192, F_DIM=1024, LOW=128, MID=32, J=8192 (p1: j=l*32+m, p2: j=4096+m*128+l)
//
// R2: k1 rewritten — W staged in LDS (no global loads in MFMA chain), 1 matrix/block,
//     grid 512. rsum dropped (k3 reads f/pf directly). k2: grid 1024 via slice-half
//     split (g as 2 partials), biases in LDS. k3: sums g partials + fp32 residual.

typedef __attribute__((ext_vector_type(8))) short bf16x8;
typedef __attribute__((ext_vector_type(4))) float f32x4;

__device__ __forceinline__ ushort f2bf(float x) {
    union { float f; uint32_t u; } v; v.f = x;
    uint32_t r = (v.u + 0x7FFFu + ((v.u >> 16) & 1u)) >> 16;
    return (ushort)r;
}
__device__ __forceinline__ ushort4 f2bf4(float4 v) {
    ushort4 o; o.x = f2bf(v.x); o.y = f2bf(v.y); o.z = f2bf(v.z); o.w = f2bf(v.w); return o;
}

// ---------------- K0: weight conversion (fp32 -> bf16) ----------------
__global__ __launch_bounds__(256) void k0_convert(
    const float* __restrict__ pgw, const float* __restrict__ wf,
    const float* __restrict__ wpf, const float* __restrict__ w2,
    ushort* __restrict__ o_pg, ushort* __restrict__ o_wf,
    ushort* __restrict__ o_wpf, ushort* __restrict__ o_w2)
{
    int i = blockIdx.x * 256 + threadIdx.x;
    const float* src; ushort* dst; int off;
    if (i < 262144)      { src = pgw; dst = o_pg;  off = i; }
    else if (i < 294912) { src = wf;  dst = o_wf;  off = i - 262144; }
    else if (i < 327680) { src = wpf; dst = o_wpf; off = i - 294912; }
    else                 { src = w2;  dst = o_w2;  off = i - 327680; }
    float4 v = ((const float4*)src)[off];
    ((ushort4*)dst)[off] = f2bf4(v);
}

// ---------------- K1: input projections (one matrix per block) ----------------
// grid 512 = mat(2) x 256 sample-blocks of 32. block 256 (4 waves).
// All MFMA operands from LDS; global loads are cooperative + 1-round register prefetch.
__global__ __launch_bounds__(256) void k1_proj(
    const float* __restrict__ f, const float* __restrict__ pf,
    const ushort* __restrict__ wf_bf, const ushort* __restrict__ wpf_bf,
    const float* __restrict__ bf_bias, const float* __restrict__ bpf_bias,
    float* __restrict__ f_lowT, ushort* __restrict__ pf_low)
{
    __shared__ ushort Wt[128 * 136];   // 34816 B, pad stride 136 (conflict-free b128)
    __shared__ ushort At[32 * 136];    // 8704 B
    const int tid = threadIdx.x;
    const int lane = tid & 63, wid = tid >> 6;
    const int q = lane >> 4, r15 = lane & 15;
    const int mat = blockIdx.x & 1;
    const int b0 = (blockIdx.x >> 1) * 32;
    const float*  A = mat ? pf : f;
    const ushort* W = mat ? wpf_bf : wf_bf;
    const float*  bias_ptr = mat ? bpf_bias : bf_bias;

    // staging maps
    const int arow = tid >> 3, akc = tid & 7;     // A: 32 rows x 8 chunks of 16 floats
    const int wrow = tid >> 1, wh  = tid & 1;     // W: 128 rows x 2 halves of 64 shorts

    const float*  aptr = A + (size_t)(b0 + arow) * 1024 + akc * 16;
    const ushort* wptr = W + (size_t)wrow * 1024 + wh * 64;

    // prefetch round 0
    float4 fa[4]; uint4 wv[8];
#pragma unroll
    for (int i = 0; i < 4; i++) fa[i] = ((const float4*)aptr)[i];
#pragma unroll
    for (int i = 0; i < 8; i++) wv[i] = ((const uint4*)wptr)[i];

    const int rb = wid >> 1, cgq = wid & 1;
    // epilogue bias prefetch (independent, issue early)
    float bias_v[4];
#pragma unroll
    for (int cg = 0; cg < 4; cg++) bias_v[cg] = bias_ptr[cgq * 64 + cg * 16 + r15];

    f32x4 c[4];
#pragma unroll
    for (int i = 0; i < 4; i++) c[i] = (f32x4){0.f, 0.f, 0.f, 0.f};

    for (int r8 = 0; r8 < 8; r8++) {
        __syncthreads();
        // store A (cvt fp32->bf16, pack 16 -> 2x b128) and W
        {
            union { ushort4 s4[4]; uint4 u4[2]; } pk;
#pragma unroll
            for (int i = 0; i < 4; i++) pk.s4[i] = f2bf4(fa[i]);
            uint4* ad = (uint4*)(At + arow * 136 + akc * 16);
            ad[0] = pk.u4[0]; ad[1] = pk.u4[1];
            uint4* wd = (uint4*)(Wt + wrow * 136 + wh * 64);
#pragma unroll
            for (int i = 0; i < 8; i++) wd[i] = wv[i];
        }
        __syncthreads();
        if (r8 < 7) {
            const int kr = (r8 + 1) * 128;
#pragma unroll
            for (int i = 0; i < 4; i++) fa[i] = ((const float4*)(aptr + kr))[i];
#pragma unroll
            for (int i = 0; i < 8; i++) wv[i] = ((const uint4*)(wptr + kr))[i];
        }
        // compute from LDS only
        bf16x8 af[4];
#pragma unroll
        for (int ks = 0; ks < 4; ks++)
            af[ks] = *(const bf16x8*)(At + (rb * 16 + r15) * 136 + ks * 32 + q * 8);
#pragma unroll
        for (int cg = 0; cg < 4; cg++) {
            const ushort* wp = Wt + (cgq * 64 + cg * 16 + r15) * 136 + q * 8;
#pragma unroll
            for (int ks = 0; ks < 4; ks++)
                c[cg] = __builtin_amdgcn_mfma_f32_16x16x32_bf16(af[ks], *(const bf16x8*)(wp + ks * 32), c[cg], 0, 0, 0);
        }
    }
    // epilogue: C rows = samples (b0 + rb*16 + q*4 + r), cols = l (cgq*64 + cg*16 + r15)
    if (mat == 0) {
#pragma unroll
        for (int cg = 0; cg < 4; cg++) {
            int l = cgq * 64 + cg * 16 + r15;
#pragma unroll
            for (int r = 0; r < 4; r++) {
                int b = b0 + rb * 16 + q * 4 + r;
                f_lowT[(size_t)l * 8192 + b] = c[cg][r] + bias_v[cg];
            }
        }
    } else {
#pragma unroll
        for (int cg = 0; cg < 4; cg++) {
            int l = cgq * 64 + cg * 16 + r15;
#pragma unroll
            for (int r = 0; r < 4; r++) {
                int b = b0 + rb * 16 + q * 4 + r;
                pf_low[(size_t)b * 128 + l] = f2bf(c[cg][r] + bias_v[cg]);
            }
        }
    }
}

// ---------------- K2: fused dynamic-weight GEMM + contraction ----------------
// grid 1024 = 128 sample-blocks(64) x grp(4) x sh(2). block 256 (4 waves x 16 samples).
// mode0: j = grp*1024 + sh*512 + sl*32 + m  (sl = l-local 0..15), scale = f_low[b,l]
//        -> h_part[(grp*2+sh)][m][b]  (partial over 16 l's)
// mode1: j = 4096 + (sh*16+sl)*128 + grp*32 + row (sl = m-local), scale = relu(sum_g h_part)
//        -> g_part[sh][b][grp*32+row]  (partial over 16 m's)
__global__ __launch_bounds__(256) void k2_dyn(
    const ushort* __restrict__ pgw_bf, const ushort* __restrict__ pf_low,
    const float* __restrict__ pg_b, const float* __restrict__ f_lowT,
    const float* __restrict__ h_in, float* __restrict__ out_hpart,
    float* __restrict__ out_g, int mode)
{
    __shared__ ushort Asl[4 * 32 * 136];   // 34816 B
    __shared__ float scale_lds[16 * 64];   // 4096 B
    __shared__ float bias_lds[512];        // 2048 B
    const int tid = threadIdx.x;
    const int lane = tid & 63, wid = tid >> 6;
    const int q = lane >> 4, r15 = lane & 15;
    const int sb = blockIdx.x >> 3;
    const int grp = (blockIdx.x >> 1) & 3;
    const int sh = blockIdx.x & 1;
    const int b0 = sb * 64;
    const int rowBase   = mode ? (4096 + sh * 2048 + grp * 32) : (grp * 1024 + sh * 512);
    const int rowStride = mode ? 128 : 32;
    const int srow = tid >> 3, skc = tid & 7;

    // stage biases (512 floats) into LDS
    if (tid < 128) {
        int sl = tid >> 3, rq = (tid & 7) * 4;
        float4 bv = *(const float4*)(pg_b + rowBase + sl * rowStride + rq);
        *(float4*)(bias_lds + sl * 32 + rq) = bv;
    }
    // stage scales (16 slices x 64 samples)
    {
        int ll = tid >> 4, bc = (tid & 15) * 4;
        float4 s;
        if (mode == 0) {
            s = *(const float4*)(f_lowT + (size_t)(grp * 32 + sh * 16 + ll) * 8192 + b0 + bc);
        } else {
            s = (float4){0.f, 0.f, 0.f, 0.f};
#pragma unroll
            for (int g = 0; g < 8; g++) {
                float4 a = *(const float4*)(h_in + (size_t)(g * 32 + sh * 16 + ll) * 8192 + b0 + bc);
                s.x += a.x; s.y += a.y; s.z += a.z; s.w += a.w;
            }
            s.x = fmaxf(s.x, 0.f); s.y = fmaxf(s.y, 0.f);
            s.z = fmaxf(s.z, 0.f); s.w = fmaxf(s.w, 0.f);
        }
        *(float4*)(scale_lds + ll * 64 + bc) = s;
    }

    // B-fragments: pf_low for this wave's 16 samples (registers, whole kernel)
    const int bw = b0 + wid * 16;
    bf16x8 bfr[4];
#pragma unroll
    for (int ks = 0; ks < 4; ks++)
        bfr[ks] = *(const bf16x8*)(pf_low + (size_t)(bw + r15) * 128 + ks * 32 + q * 8);

    f32x4 acc[2];
    acc[0] = (f32x4){0.f, 0.f, 0.f, 0.f};
    acc[1] = (f32x4){0.f, 0.f, 0.f, 0.f};

    uint4 st[8];
#pragma unroll
    for (int sl = 0; sl < 4; sl++) {
        const ushort* src = pgw_bf + (size_t)(rowBase + sl * rowStride + srow) * 128 + skc * 16;
        st[sl * 2 + 0] = ((const uint4*)src)[0];
        st[sl * 2 + 1] = ((const uint4*)src)[1];
    }

    for (int rnd = 0; rnd < 4; rnd++) {
        __syncthreads();
#pragma unroll
        for (int sl = 0; sl < 4; sl++) {
            uint4* d = (uint4*)(Asl + sl * 4352 + srow * 136 + skc * 16);
            d[0] = st[sl * 2 + 0]; d[1] = st[sl * 2 + 1];
        }
        __syncthreads();
        if (rnd < 3) {
#pragma unroll
            for (int sl = 0; sl < 4; sl++) {
                int slice = (rnd + 1) * 4 + sl;
                const ushort* src = pgw_bf + (size_t)(rowBase + slice * rowStride + srow) * 128 + skc * 16;
                st[sl * 2 + 0] = ((const uint4*)src)[0];
                st[sl * 2 + 1] = ((const uint4*)src)[1];
            }
        }
#pragma unroll
        for (int sl = 0; sl < 4; sl++) {
            const int sl_loc = rnd * 4 + sl;
            const float s = scale_lds[sl_loc * 64 + wid * 16 + r15];
            const ushort* ab = Asl + sl * 4352 + r15 * 136 + q * 8;
#pragma unroll
            for (int half = 0; half < 2; half++) {
                f32x4 cc = (f32x4){0.f, 0.f, 0.f, 0.f};
                const ushort* ah = ab + half * 2176;
#pragma unroll
                for (int ks = 0; ks < 4; ks++)
                    cc = __builtin_amdgcn_mfma_f32_16x16x32_bf16(*(const bf16x8*)(ah + ks * 32), bfr[ks], cc, 0, 0, 0);
                f32x4 bias = *(const f32x4*)(bias_lds + sl_loc * 32 + half * 16 + q * 4);
                acc[half][0] += s * (cc[0] + bias[0]);
                acc[half][1] += s * (cc[1] + bias[1]);
                acc[half][2] += s * (cc[2] + bias[2]);
                acc[half][3] += s * (cc[3] + bias[3]);
            }
        }
    }
    // epilogue: C rows = j-local (half*16+q*4+r), cols = b (bw+r15)
    if (mode == 0) {
        float* dst = out_hpart + (size_t)(grp * 2 + sh) * 262144;
#pragma unroll
        for (int half = 0; half < 2; half++)
#pragma unroll
            for (int r = 0; r < 4; r++)
                dst[(size_t)(half * 16 + q * 4 + r) * 8192 + bw + r15] = acc[half][r];
    } else {
        float* dst = out_g + (size_t)sh * 1048576;
#pragma unroll
        for (int half = 0; half < 2; half++)
#pragma unroll
            for (int r = 0; r < 4; r++)
                dst[(size_t)(bw + r15) * 128 + grp * 32 + half * 16 + q * 4 + r] = acc[half][r];
    }
}

// ---------------- K3: final projection + bias + fp32 residual ----------------
// grid 2048 (128 m-blocks x 16 n-blocks), block 256 (4 waves). tile M=64, N=64.
__global__ __launch_bounds__(256) void k3_out(
    const float* __restrict__ g0, const float* __restrict__ g1,
    const ushort* __restrict__ w2_bf, const float* __restrict__ b2,
    const float* __restrict__ f, const float* __restrict__ pf,
    float* __restrict__ out)
{
    __shared__ ushort Ag[64 * 136];
    __shared__ ushort Bw[64 * 136];
    const int tid = threadIdx.x;
    const int lane = tid & 63, wid = tid >> 6;
    const int q = lane >> 4, r15 = lane & 15;
    const int mb = blockIdx.x >> 4, nb = blockIdx.x & 15;
    const int b0 = mb * 64, n0 = nb * 64;
    {
        int row = tid >> 2, kc = tid & 3;     // 64 rows x 4 chunks of 32
        const float4* gp0 = (const float4*)(g0 + (size_t)(b0 + row) * 128 + kc * 32);
        const float4* gp1 = (const float4*)(g1 + (size_t)(b0 + row) * 128 + kc * 32);
        ushort* ad = Ag + row * 136 + kc * 32;
#pragma unroll
        for (int i = 0; i < 8; i++) {
            float4 a = gp0[i], b = gp1[i];
            float4 s; s.x = a.x + b.x; s.y = a.y + b.y; s.z = a.z + b.z; s.w = a.w + b.w;
            ((ushort4*)ad)[i] = f2bf4(s);
        }
        const uint4* wp = (const uint4*)(w2_bf + (size_t)(n0 + row) * 128 + kc * 32);
        uint4* bd = (uint4*)(Bw + row * 136 + kc * 32);
#pragma unroll
        for (int i = 0; i < 4; i++) bd[i] = wp[i];
    }
    // prefetch residuals + bias (independent of LDS; overlaps barrier + MFMA)
    float rsv[16]; float bias_v[4];
#pragma unroll
    for (int cg = 0; cg < 4; cg++) {
        int n = n0 + cg * 16 + r15;
        bias_v[cg] = b2[n];
#pragma unroll
        for (int r = 0; r < 4; r++) {
            int b = b0 + wid * 16 + q * 4 + r;
            rsv[cg * 4 + r] = f[(size_t)b * 1024 + n] + pf[(size_t)b * 1024 + n];
        }
    }
    __syncthreads();
    const int rw = wid * 16;
    bf16x8 af[4];
#pragma unroll
    for (int ks = 0; ks < 4; ks++)
        af[ks] = *(const bf16x8*)(Ag + (rw + r15) * 136 + ks * 32 + q * 8);
    f32x4 c[4];
#pragma unroll
    for (int i = 0; i < 4; i++) c[i] = (f32x4){0.f, 0.f, 0.f, 0.f};
#pragma unroll
    for (int cg = 0; cg < 4; cg++) {
        const ushort* bp = Bw + (cg * 16 + r15) * 136 + q * 8;
#pragma unroll
        for (int ks = 0; ks < 4; ks++)
            c[cg] = __builtin_amdgcn_mfma_f32_16x16x32_bf16(af[ks], *(const bf16x8*)(bp + ks * 32), c[cg], 0, 0, 0);
    }
#pragma unroll
    for (int cg = 0; cg < 4; cg++) {
        int n = n0 + cg * 16 + r15;
#pragma unroll
        for (int r = 0; r < 4; r++) {
            int b = b0 + rw + q * 4 + r;
            out[(size_t)b * 1024 + n] = c[cg][r] + bias_v[cg] + rsv[cg * 4 + r];
        }
    }
}

// ---------------- launch ----------------
extern "C" void kernel_launch(void* const* d_in, const int* in_sizes, int n_in,
                              void* d_out, int out_size, void* d_ws, size_t ws_size,
                              hipStream_t stream)
{
    const float* f    = (const float*)d_in[0];
    const float* pf   = (const float*)d_in[1];
    const float* wf   = (const float*)d_in[2];
    const float* bfb  = (const float*)d_in[3];
    const float* wpf  = (const float*)d_in[4];
    const float* bpfb = (const float*)d_in[5];
    const float* w2   = (const float*)d_in[6];
    const float* b2   = (const float*)d_in[7];
    const float* pgw  = (const float*)d_in[8];
    const float* pgb  = (const float*)d_in[9];

    char* ws = (char*)d_ws;
    ushort* pgw_bf = (ushort*)(ws + 0);          // 2 MB
    ushort* wf_bf  = (ushort*)(ws + 2097152);    // 256 KB
    ushort* wpf_bf = (ushort*)(ws + 2359296);    // 256 KB
    ushort* w2_bf  = (ushort*)(ws + 2621440);    // 256 KB
    float*  f_lowT = (float*)(ws + 2883584);     // 4 MB  [l][b]
    ushort* pf_low = (ushort*)(ws + 7077888);    // 2 MB  [b][l]
    float*  h_part = (float*)(ws + 9175040);     // 8 MB  [8][32][8192]
    float*  g_part = (float*)(ws + 17563648);    // 8 MB  [2][8192][128]
    float*  out    = (float*)d_out;

    k0_convert<<<dim3(1408), dim3(256), 0, stream>>>(pgw, wf, wpf, w2, pgw_bf, wf_bf, wpf_bf, w2_bf);
    k1_proj<<<dim3(512), dim3(256), 0, stream>>>(f, pf, wf_bf, wpf_bf, bfb, bpfb, f_lowT, pf_low);
    k2_dyn<<<dim3(1024), dim3(256), 0, stream>>>(pgw_bf, pf_low, pgb, f_lowT, h_part, h_part, g_part, 0);
    k2_dyn<<<dim3(1024), dim3(256), 0, stream>>>(pgw_bf, pf_low, pgb, f_lowT, h_part, h_part, g_part, 1);
    k3_out<<<dim3(2048), dim3(256), 0, stream>>>(g_part, g_part + 1048576, w2_bf, b2, f, pf, out);
}

// Round 3
// 259.519 us; speedup vs baseline: 1.1663x; 1.1663x over previous
//
#include <hip/hip_runtime.h>
#include <hip/hip_bf16.h>
#include <stdint.h>

// DynamicFc R3: all global accesses wave-contiguous (lane i -> base + 16B*i).
// k0 emits fragment-major weight images; k2 loads MFMA A-frags DIRECTLY from
// L2-resident images into VGPRs (depth-4 register ring), >=64 samples/wave.
// B=8192, F=1024, LOW=128, MID=32. p1: j=l*32+m (j<4096), p2: j=4096+m*128+l.
//
// Fragment-major image layout (16x16x32 bf16 MFMA):
//   chunk(T, ks)[lane] = 8 ushorts = W[row = T*16 + (lane&15)][k = ks*32 + (lane>>4)*8 .. +8]
//   -> one global_load_dwordx4 per lane, 1KB contiguous per (T,ks) chunk.

typedef __attribute__((ext_vector_type(8))) short bf16x8;
typedef __attribute__((ext_vector_type(4))) float f32x4;

#define MFMA(a, b, c) __builtin_amdgcn_mfma_f32_16x16x32_bf16((a), (b), (c), 0, 0, 0)

__device__ __forceinline__ ushort f2bf(float x) {
    union { float f; uint32_t u; } v; v.f = x;
    return (ushort)((v.u + 0x7FFFu + ((v.u >> 16) & 1u)) >> 16);
}
__device__ __forceinline__ ushort4 f2bf4(float4 v) {
    ushort4 o; o.x = f2bf(v.x); o.y = f2bf(v.y); o.z = f2bf(v.z); o.w = f2bf(v.w); return o;
}

// ---------------- K0: convert + fragment-major re-layout ----------------
// pg_img: T=0..511 tiles over j (p1 then p2), [T][ks 0..3][lane][8ush]  (2 MB)
// w_img:  [mat 2][lt 0..7][ks 0..31][lane][8ush]   (512 KB)   rows=l, K=1024
// w2_img: [nt 0..63][ks 0..3][lane][8ush]          (256 KB)   rows=n, K=128
__global__ __launch_bounds__(256) void k0_convert(
    const float* __restrict__ pgw, const float* __restrict__ wf,
    const float* __restrict__ wpf, const float* __restrict__ w2,
    ushort* __restrict__ pg_img, ushort* __restrict__ w_img, ushort* __restrict__ w2_img)
{
    int cid = blockIdx.x * 256 + threadIdx.x;   // 704*256 = 180224
    const float* src; ushort* dst;
    if (cid < 131072) {                                  // pg: 512*4*64
        int lane = cid & 63, ks = (cid >> 6) & 3, T = cid >> 8;
        int j = T * 16 + (lane & 15), k = ks * 32 + (lane >> 4) * 8;
        src = pgw + (size_t)j * 128 + k;
        dst = pg_img + (size_t)cid * 8;
    } else if (cid < 163840) {                           // wf/wpf: 2*8*32*64
        int c = cid - 131072;
        int lane = c & 63, ks = (c >> 6) & 31, lt = (c >> 11) & 7, mat = c >> 14;
        int l = lt * 16 + (lane & 15), k = ks * 32 + (lane >> 4) * 8;
        src = (mat ? wpf : wf) + (size_t)l * 1024 + k;
        dst = w_img + (size_t)c * 8;
    } else {                                             // w2: 64*4*64
        int c = cid - 163840;
        int lane = c & 63, ks = (c >> 6) & 3, nt = c >> 8;
        int n = nt * 16 + (lane & 15), k = ks * 32 + (lane >> 4) * 8;
        src = w2 + (size_t)n * 128 + k;
        dst = w2_img + (size_t)c * 8;
    }
    float4 a = ((const float4*)src)[0], b = ((const float4*)src)[1];
    ((ushort4*)dst)[0] = f2bf4(a);
    ((ushort4*)dst)[1] = f2bf4(b);
}

// ---------------- K1: input projections ----------------
// grid 1024 = sb(512 blocks of 16 samples) x mat(2). block 256 (4 waves).
// A tile (16x1024 bf16) staged once in LDS (single barrier); W fragment-streamed
// from L2 image direct to VGPR (ring depth 4). wave w owns l in [w*32, w*32+32).
__global__ __launch_bounds__(256) void k1_proj(
    const float* __restrict__ f, const float* __restrict__ pf,
    const ushort* __restrict__ w_img,
    const float* __restrict__ bf_bias, const float* __restrict__ bpf_bias,
    float* __restrict__ f_low /*[l][b] fp32*/, ushort* __restrict__ pf_low /*[b][l] bf16*/)
{
    __shared__ __align__(16) ushort A[16 * 1032];   // 33 KB, stride 1032 ush
    const int tid = threadIdx.x;
    const int lane = tid & 63, wid = tid >> 6;
    const int q = lane >> 4, r15 = lane & 15;
    const int mat = blockIdx.x & 1;
    const int b0 = (blockIdx.x >> 1) * 16;
    const float* src = mat ? pf : f;
    const float* bias_ptr = mat ? bpf_bias : bf_bias;

    // stage A: instr j covers row j; thread t -> floats [4t, 4t+4)  (wave-contiguous)
#pragma unroll
    for (int ch = 0; ch < 2; ch++) {
        float4 v[8];
#pragma unroll
        for (int rr = 0; rr < 8; rr++)
            v[rr] = *(const float4*)(src + (size_t)(b0 + ch * 8 + rr) * 1024 + tid * 4);
#pragma unroll
        for (int rr = 0; rr < 8; rr++)
            *(ushort4*)(A + (ch * 8 + rr) * 1032 + tid * 4) = f2bf4(v[rr]);
    }
    // epilogue bias prefetch
    float bias_v[2];
#pragma unroll
    for (int j = 0; j < 2; j++) bias_v[j] = bias_ptr[wid * 32 + j * 16 + r15];
    __syncthreads();

    const int lt0 = wid * 2;
    const ushort* wb = w_img + (size_t)mat * 131072;   // mat*8*32*512
    bf16x8 wfr[4][2];
#pragma unroll
    for (int pre = 0; pre < 4; pre++)
#pragma unroll
        for (int j = 0; j < 2; j++)
            wfr[pre][j] = *(const bf16x8*)(wb + ((size_t)(lt0 + j) * 32 + pre) * 512 + lane * 8);

    f32x4 c[2];
    c[0] = (f32x4){0.f, 0.f, 0.f, 0.f};
    c[1] = (f32x4){0.f, 0.f, 0.f, 0.f};
    for (int ks = 0; ks < 32; ks++) {
        int cur = ks & 3;
        bf16x8 af = *(const bf16x8*)(A + r15 * 1032 + ks * 32 + q * 8);
        c[0] = MFMA(af, wfr[cur][0], c[0]);
        c[1] = MFMA(af, wfr[cur][1], c[1]);
        if (ks + 4 < 32) {
#pragma unroll
            for (int j = 0; j < 2; j++)
                wfr[cur][j] = *(const bf16x8*)(wb + ((size_t)(lt0 + j) * 32 + (ks + 4)) * 512 + lane * 8);
        }
    }
    // C rows = b (q*4+r), cols = l (wid*32 + j*16 + r15). Line-merged scatter writes.
    if (mat == 0) {
#pragma unroll
        for (int j = 0; j < 2; j++) {
            int l = wid * 32 + j * 16 + r15;
#pragma unroll
            for (int r = 0; r < 4; r++)
                f_low[(size_t)l * 8192 + b0 + q * 4 + r] = c[j][r] + bias_v[j];
        }
    } else {
#pragma unroll
        for (int j = 0; j < 2; j++) {
            int l = wid * 32 + j * 16 + r15;
#pragma unroll
            for (int r = 0; r < 4; r++)
                pf_low[(size_t)(b0 + q * 4 + r) * 128 + l] = f2bf(c[j][r] + bias_v[j]);
        }
    }
}

// ---------------- K2a: h partials ----------------
// grid 256 = sb(128 of 64 samples) x g(2: l-half). block 256; wave (p=l-parity, mh=m-half).
// Each wave: 64 samples, 32 row-tiles, A-frags direct from pg_img (ring 4).
__global__ __launch_bounds__(256) void k2_h(
    const ushort* __restrict__ pg_img, const ushort* __restrict__ pf_low,
    const float* __restrict__ pg_b, const float* __restrict__ f_low,
    float* __restrict__ h_part /*[4][32][8192]*/)
{
    __shared__ __align__(16) float flow[64 * 64];
    __shared__ __align__(16) float biasl[2048];
    const int tid = threadIdx.x;
    const int lane = tid & 63, wid = tid >> 6;
    const int q = lane >> 4, r15 = lane & 15;
    const int g = blockIdx.x & 1, b0 = (blockIdx.x >> 1) * 64;
    const int p = wid >> 1, mh = wid & 1;
    {   // stage f_low slice [64 l][64 b] and biases (both wave-contiguous-ish, small)
        int row = tid >> 2, c4 = (tid & 3) * 16;
        const float* sp = f_low + (size_t)(g * 64 + row) * 8192 + b0 + c4;
        float* dp = flow + row * 64 + c4;
#pragma unroll
        for (int i = 0; i < 4; i++) ((float4*)dp)[i] = ((const float4*)sp)[i];
        const float* bp = pg_b + g * 2048 + tid * 8;
        ((float4*)(biasl + tid * 8))[0] = ((const float4*)bp)[0];
        ((float4*)(biasl + tid * 8))[1] = ((const float4*)bp)[1];
    }
    // B-frags: pf_low for 64 samples (64 VGPR, resident)
    bf16x8 bfr[4][4];
#pragma unroll
    for (int ct = 0; ct < 4; ct++)
#pragma unroll
        for (int ks = 0; ks < 4; ks++)
            bfr[ct][ks] = *(const bf16x8*)(pf_low + (size_t)(b0 + ct * 16 + r15) * 128 + ks * 32 + q * 8);
    __syncthreads();

    f32x4 hacc[4];
#pragma unroll
    for (int i = 0; i < 4; i++) hacc[i] = (f32x4){0.f, 0.f, 0.f, 0.f};
    bf16x8 af[4][4];
#pragma unroll
    for (int pre = 0; pre < 4; pre++) {
        const ushort* ap = pg_img + (size_t)(g * 128 + (p + 2 * pre) * 2 + mh) * 2048;
#pragma unroll
        for (int ks = 0; ks < 4; ks++) af[pre][ks] = *(const bf16x8*)(ap + ks * 512 + lane * 8);
    }
    for (int it = 0; it < 32; it++) {
        const int cur = it & 3, ll = p + 2 * it;
        f32x4 bv = *(const f32x4*)(biasl + ll * 32 + mh * 16 + q * 4);
#pragma unroll
        for (int ct = 0; ct < 4; ct++) {
            f32x4 cc = (f32x4){0.f, 0.f, 0.f, 0.f};
#pragma unroll
            for (int ks = 0; ks < 4; ks++) cc = MFMA(af[cur][ks], bfr[ct][ks], cc);
            float s = flow[ll * 64 + ct * 16 + r15];
#pragma unroll
            for (int r = 0; r < 4; r++) hacc[ct][r] += s * (cc[r] + bv[r]);
        }
        if (it + 4 < 32) {
            const ushort* ap = pg_img + (size_t)(g * 128 + (p + 2 * (it + 4)) * 2 + mh) * 2048;
#pragma unroll
            for (int ks = 0; ks < 4; ks++) af[cur][ks] = *(const bf16x8*)(ap + ks * 512 + lane * 8);
        }
    }
    float* hp = h_part + (size_t)(g * 2 + p) * 262144 + (size_t)(mh * 16 + q * 4) * 8192 + b0 + r15;
#pragma unroll
    for (int ct = 0; ct < 4; ct++)
#pragma unroll
        for (int r = 0; r < 4; r++)
            hp[(size_t)r * 8192 + ct * 16] = hacc[ct][r];
}

// ---------------- K2b: g partials ----------------
// grid 256 = sb(128) x g(2: m-half). wave w owns l-tiles {w, w+4}.
__global__ __launch_bounds__(256) void k2_g(
    const ushort* __restrict__ pg_img, const ushort* __restrict__ pf_low,
    const float* __restrict__ pg_b, const float* __restrict__ h_part,
    float* __restrict__ g_part /*[2][8192][128]*/)
{
    __shared__ __align__(16) float hl[16 * 64];
    __shared__ __align__(16) float biasl[2048];
    const int tid = threadIdx.x;
    const int lane = tid & 63, wid = tid >> 6;
    const int q = lane >> 4, r15 = lane & 15;
    const int g = blockIdx.x & 1, b0 = (blockIdx.x >> 1) * 64;
    {   // stage relu(sum of 4 h partials) for m in [g*16, +16)
        int m_loc = tid >> 4, c = (tid & 15) * 4;
        float4 s = (float4){0.f, 0.f, 0.f, 0.f};
#pragma unroll
        for (int pp = 0; pp < 4; pp++) {
            float4 a = *(const float4*)(h_part + (size_t)pp * 262144 + (size_t)(g * 16 + m_loc) * 8192 + b0 + c);
            s.x += a.x; s.y += a.y; s.z += a.z; s.w += a.w;
        }
        s.x = fmaxf(s.x, 0.f); s.y = fmaxf(s.y, 0.f); s.z = fmaxf(s.z, 0.f); s.w = fmaxf(s.w, 0.f);
        *(float4*)(hl + m_loc * 64 + c) = s;
        const float* bp = pg_b + 4096 + g * 2048 + tid * 8;
        ((float4*)(biasl + tid * 8))[0] = ((const float4*)bp)[0];
        ((float4*)(biasl + tid * 8))[1] = ((const float4*)bp)[1];
    }
    bf16x8 bfr[4][4];
#pragma unroll
    for (int ct = 0; ct < 4; ct++)
#pragma unroll
        for (int ks = 0; ks < 4; ks++)
            bfr[ct][ks] = *(const bf16x8*)(pf_low + (size_t)(b0 + ct * 16 + r15) * 128 + ks * 32 + q * 8);
    __syncthreads();

    f32x4 gacc[2][4];
#pragma unroll
    for (int i = 0; i < 2; i++)
#pragma unroll
        for (int jj = 0; jj < 4; jj++) gacc[i][jj] = (f32x4){0.f, 0.f, 0.f, 0.f};
    bf16x8 af[4][4];
#pragma unroll
    for (int pre = 0; pre < 4; pre++) {
        const ushort* ap = pg_img + (size_t)(256 + (g * 16 + (pre >> 1)) * 8 + (pre & 1) * 4 + wid) * 2048;
#pragma unroll
        for (int ks = 0; ks < 4; ks++) af[pre][ks] = *(const bf16x8*)(ap + ks * 512 + lane * 8);
    }
    for (int it = 0; it < 32; it++) {
        const int cur = it & 3, m_loc = it >> 1, lt_hi = it & 1;
        const int lt = lt_hi * 4 + wid;
        f32x4 bv = *(const f32x4*)(biasl + m_loc * 128 + lt * 16 + q * 4);
#pragma unroll
        for (int ct = 0; ct < 4; ct++) {
            f32x4 cc = (f32x4){0.f, 0.f, 0.f, 0.f};
#pragma unroll
            for (int ks = 0; ks < 4; ks++) cc = MFMA(af[cur][ks], bfr[ct][ks], cc);
            float s = hl[m_loc * 64 + ct * 16 + r15];
#pragma unroll
            for (int r = 0; r < 4; r++) gacc[lt_hi][ct][r] += s * (cc[r] + bv[r]);
        }
        if (it + 4 < 32) {
            int it4 = it + 4;
            const ushort* ap = pg_img + (size_t)(256 + (g * 16 + (it4 >> 1)) * 8 + (it4 & 1) * 4 + wid) * 2048;
#pragma unroll
            for (int ks = 0; ks < 4; ks++) af[cur][ks] = *(const bf16x8*)(ap + ks * 512 + lane * 8);
        }
    }
    // write g_part[g][b][l]: line [b][l..l+16) fully written by this wave -> L2 merges
    float* gp = g_part + (size_t)g * 1048576;
#pragma unroll
    for (int lt_hi = 0; lt_hi < 2; lt_hi++)
#pragma unroll
        for (int ct = 0; ct < 4; ct++) {
            int b = b0 + ct * 16 + r15;
            int l = (lt_hi * 4 + wid) * 16 + q * 4;
#pragma unroll
            for (int r = 0; r < 4; r++)
                gp[(size_t)b * 128 + l + r] = gacc[lt_hi][ct][r];
        }
}

// ---------------- K3: out = g@W2^T + b2 + f + pf ----------------
// grid 512 = sb(128 of 64 samples) x nb(4 of 256 n). block 256 (4 waves, wave = 4 n-tiles).
__global__ __launch_bounds__(256) void k3_out(
    const float* __restrict__ g_part, const ushort* __restrict__ w2_img,
    const float* __restrict__ b2, const float* __restrict__ f,
    const float* __restrict__ pf, float* __restrict__ out)
{
    __shared__ __align__(16) ushort Ag[64 * 136];
    const int tid = threadIdx.x;
    const int lane = tid & 63, wid = tid >> 6;
    const int q = lane >> 4, r15 = lane & 15;
    const int b0 = (blockIdx.x >> 2) * 64, n0 = (blockIdx.x & 3) * 256;
    // stage A = g0+g1 (wave-contiguous reads: flat float4 index)
#pragma unroll
    for (int j = 0; j < 8; j++) {
        int fl = j * 256 + tid;
        int b = fl >> 5, l4 = fl & 31;
        const float* gp = g_part + (size_t)(b0 + b) * 128 + l4 * 4;
        float4 a = *(const float4*)gp;
        float4 bb = *(const float4*)(gp + 1048576);
        float4 s; s.x = a.x + bb.x; s.y = a.y + bb.y; s.z = a.z + bb.z; s.w = a.w + bb.w;
        *(ushort4*)(Ag + b * 136 + l4 * 4) = f2bf4(s);
    }
    __syncthreads();
    bf16x8 afr[4][4];
#pragma unroll
    for (int mt = 0; mt < 4; mt++)
#pragma unroll
        for (int ks = 0; ks < 4; ks++)
            afr[mt][ks] = *(const bf16x8*)(Ag + (mt * 16 + r15) * 136 + ks * 32 + q * 8);

    const int ntb = (blockIdx.x & 3) * 16 + wid * 4;
    bf16x8 wfr[2][4];
    float rf[2][16], rp[2][16], bias_v[2];
    {
        int n = n0 + (wid * 4 + 0) * 16 + r15;
        bias_v[0] = b2[n];
#pragma unroll
        for (int ks = 0; ks < 4; ks++)
            wfr[0][ks] = *(const bf16x8*)(w2_img + ((size_t)(ntb + 0) * 4 + ks) * 512 + lane * 8);
#pragma unroll
        for (int mt = 0; mt < 4; mt++)
#pragma unroll
            for (int r = 0; r < 4; r++) {
                int b = b0 + mt * 16 + q * 4 + r;
                rf[0][mt * 4 + r] = f[(size_t)b * 1024 + n];
                rp[0][mt * 4 + r] = pf[(size_t)b * 1024 + n];
            }
    }
    for (int i = 0; i < 4; i++) {
        const int cur = i & 1, nxt = cur ^ 1;
        if (i < 3) {
            int n = n0 + (wid * 4 + i + 1) * 16 + r15;
            bias_v[nxt] = b2[n];
#pragma unroll
            for (int ks = 0; ks < 4; ks++)
                wfr[nxt][ks] = *(const bf16x8*)(w2_img + ((size_t)(ntb + i + 1) * 4 + ks) * 512 + lane * 8);
#pragma unroll
            for (int mt = 0; mt < 4; mt++)
#pragma unroll
                for (int r = 0; r < 4; r++) {
                    int b = b0 + mt * 16 + q * 4 + r;
                    rf[nxt][mt * 4 + r] = f[(size_t)b * 1024 + n];
                    rp[nxt][mt * 4 + r] = pf[(size_t)b * 1024 + n];
                }
        }
        f32x4 cc[4];
#pragma unroll
        for (int mt = 0; mt < 4; mt++) cc[mt] = (f32x4){0.f, 0.f, 0.f, 0.f};
#pragma unroll
        for (int mt = 0; mt < 4; mt++)
#pragma unroll
            for (int ks = 0; ks < 4; ks++) cc[mt] = MFMA(afr[mt][ks], wfr[cur][ks], cc[mt]);
        int n = n0 + (wid * 4 + i) * 16 + r15;
#pragma unroll
        for (int mt = 0; mt < 4; mt++)
#pragma unroll
            for (int r = 0; r < 4; r++) {
                int b = b0 + mt * 16 + q * 4 + r;
                out[(size_t)b * 1024 + n] = cc[mt][r] + bias_v[cur] + rf[cur][mt * 4 + r] + rp[cur][mt * 4 + r];
            }
    }
}

// ---------------- launch ----------------
extern "C" void kernel_launch(void* const* d_in, const int* in_sizes, int n_in,
                              void* d_out, int out_size, void* d_ws, size_t ws_size,
                              hipStream_t stream)
{
    const float* f    = (const float*)d_in[0];
    const float* pf   = (const float*)d_in[1];
    const float* wf   = (const float*)d_in[2];
    const float* bfb  = (const float*)d_in[3];
    const float* wpf  = (const float*)d_in[4];
    const float* bpfb = (const float*)d_in[5];
    const float* w2   = (const float*)d_in[6];
    const float* b2   = (const float*)d_in[7];
    const float* pgw  = (const float*)d_in[8];
    const float* pgb  = (const float*)d_in[9];

    char* ws = (char*)d_ws;
    ushort* pg_img = (ushort*)(ws + 0);          // 2 MB
    ushort* w_img  = (ushort*)(ws + 2097152);    // 512 KB
    ushort* w2_img = (ushort*)(ws + 2621440);    // 256 KB
    float*  f_low  = (float*)(ws + 2883584);     // 4 MB  [l][b]
    ushort* pf_low = (ushort*)(ws + 7077888);    // 2 MB  [b][l]
    float*  h_part = (float*)(ws + 9175040);     // 4 MB  [4][32][8192]
    float*  g_part = (float*)(ws + 13369344);    // 8 MB  [2][8192][128]
    float*  out    = (float*)d_out;

    k0_convert<<<dim3(704), dim3(256), 0, stream>>>(pgw, wf, wpf, w2, pg_img, w_img, w2_img);
    k1_proj<<<dim3(1024), dim3(256), 0, stream>>>(f, pf, w_img, bfb, bpfb, f_low, pf_low);
    k2_h<<<dim3(256), dim3(256), 0, stream>>>(pg_img, pf_low, pgb, f_low, h_part);
    k2_g<<<dim3(256), dim3(256), 0, stream>>>(pg_img, pf_low, pgb, h_part, g_part);
    k3_out<<<dim3(512), dim3(256), 0, stream>>>(g_part, w2_img, b2, f, pf, out);
}

// Round 4
// 206.597 us; speedup vs baseline: 1.4650x; 1.2562x over previous
//
#include <hip/hip_runtime.h>
#include <hip/hip_bf16.h>
#include <stdint.h>

// DynamicFc R4: R3 structure, two systemic fixes:
//  (1) ALL register-array loops fully unrolled -> static indices -> no scratch
//      spills (R3: af[4][4]/bfr[4][4] with dynamic `cur` spilled; WRITE_SIZE 81MB).
//  (2) Occupancy: 1024-2048 blocks/kernel, ~100 VGPR, 4+ blocks/CU.
// B=8192, F=1024, LOW=128, MID=32. p1: j=l*32+m (j<4096), p2: j=4096+m*128+l.
// Fragment-major images: chunk(T,ks)[lane][8] = W[T*16+(lane&15)][ks*32+(lane>>4)*8..+8]

typedef __attribute__((ext_vector_type(8))) short bf16x8;
typedef __attribute__((ext_vector_type(4))) float f32x4;

#define MFMA(a, b, c) __builtin_amdgcn_mfma_f32_16x16x32_bf16((a), (b), (c), 0, 0, 0)

__device__ __forceinline__ ushort f2bf(float x) {
    union { float f; uint32_t u; } v; v.f = x;
    return (ushort)((v.u + 0x7FFFu + ((v.u >> 16) & 1u)) >> 16);
}
__device__ __forceinline__ ushort4 f2bf4(float4 v) {
    ushort4 o; o.x = f2bf(v.x); o.y = f2bf(v.y); o.z = f2bf(v.z); o.w = f2bf(v.w); return o;
}

// ---------------- K0: convert + fragment-major re-layout ----------------
__global__ __launch_bounds__(256) void k0_convert(
    const float* __restrict__ pgw, const float* __restrict__ wf,
    const float* __restrict__ wpf, const float* __restrict__ w2,
    ushort* __restrict__ pg_img, ushort* __restrict__ w_img, ushort* __restrict__ w2_img)
{
    int cid = blockIdx.x * 256 + threadIdx.x;   // 704*256 = 180224
    const float* src; ushort* dst;
    if (cid < 131072) {                                  // pg: 512*4*64
        int lane = cid & 63, ks = (cid >> 6) & 3, T = cid >> 8;
        int j = T * 16 + (lane & 15), k = ks * 32 + (lane >> 4) * 8;
        src = pgw + (size_t)j * 128 + k;
        dst = pg_img + (size_t)cid * 8;
    } else if (cid < 163840) {                           // wf/wpf: 2*8*32*64
        int c = cid - 131072;
        int lane = c & 63, ks = (c >> 6) & 31, lt = (c >> 11) & 7, mat = c >> 14;
        int l = lt * 16 + (lane & 15), k = ks * 32 + (lane >> 4) * 8;
        src = (mat ? wpf : wf) + (size_t)l * 1024 + k;
        dst = w_img + (size_t)c * 8;
    } else {                                             // w2: 64*4*64
        int c = cid - 163840;
        int lane = c & 63, ks = (c >> 6) & 3, nt = c >> 8;
        int n = nt * 16 + (lane & 15), k = ks * 32 + (lane >> 4) * 8;
        src = w2 + (size_t)n * 128 + k;
        dst = w2_img + (size_t)c * 8;
    }
    float4 a = ((const float4*)src)[0], b = ((const float4*)src)[1];
    ((ushort4*)dst)[0] = f2bf4(a);
    ((ushort4*)dst)[1] = f2bf4(b);
}

// ---------------- K1: input projections ----------------
// grid 1024 = sb(512 of 16 samples) x mat(2). block 256 (4 waves).
__global__ __launch_bounds__(256) void k1_proj(
    const float* __restrict__ f, const float* __restrict__ pf,
    const ushort* __restrict__ w_img,
    const float* __restrict__ bf_bias, const float* __restrict__ bpf_bias,
    float* __restrict__ f_low /*[l][b] f32*/, ushort* __restrict__ pf_img /*frag-major*/)
{
    __shared__ __align__(16) ushort As[16 * 1032];
    __shared__ __align__(16) ushort Tr[16 * 136];
    const int tid = threadIdx.x;
    const int lane = tid & 63, wid = tid >> 6;
    const int q = lane >> 4, r15 = lane & 15;
    const int mat = blockIdx.x & 1;
    const int b0 = (blockIdx.x >> 1) * 16;
    const float* src = mat ? pf : f;
    const float* bias_ptr = mat ? bpf_bias : bf_bias;

#pragma unroll
    for (int ch = 0; ch < 2; ch++) {
        float4 v[8];
#pragma unroll
        for (int rr = 0; rr < 8; rr++)
            v[rr] = *(const float4*)(src + (size_t)(b0 + ch * 8 + rr) * 1024 + tid * 4);
#pragma unroll
        for (int rr = 0; rr < 8; rr++)
            *(ushort4*)(As + (ch * 8 + rr) * 1032 + tid * 4) = f2bf4(v[rr]);
    }
    float bias_v[2];
#pragma unroll
    for (int j = 0; j < 2; j++) bias_v[j] = bias_ptr[wid * 32 + j * 16 + r15];
    __syncthreads();

    const int lt0 = wid * 2;
    const ushort* wb = w_img + (size_t)mat * 131072;
    bf16x8 wfr[4][2];
#pragma unroll
    for (int pre = 0; pre < 4; pre++)
#pragma unroll
        for (int j = 0; j < 2; j++)
            wfr[pre][j] = *(const bf16x8*)(wb + ((size_t)(lt0 + j) * 32 + pre) * 512 + lane * 8);

    f32x4 c[2];
    c[0] = (f32x4){0.f, 0.f, 0.f, 0.f};
    c[1] = (f32x4){0.f, 0.f, 0.f, 0.f};
#pragma unroll
    for (int ks = 0; ks < 32; ks++) {          // FULL unroll -> static ring indices
        const int cur = ks & 3;
        bf16x8 af = *(const bf16x8*)(As + r15 * 1032 + ks * 32 + q * 8);
        c[0] = MFMA(af, wfr[cur][0], c[0]);
        c[1] = MFMA(af, wfr[cur][1], c[1]);
        if (ks + 4 < 32) {
#pragma unroll
            for (int j = 0; j < 2; j++)
                wfr[cur][j] = *(const bf16x8*)(wb + ((size_t)(lt0 + j) * 32 + (ks + 4)) * 512 + lane * 8);
        }
    }
    // C: row = b_local (q*4+r), col = l (wid*32 + j*16 + r15)
    if (mat == 0) {
#pragma unroll
        for (int j = 0; j < 2; j++) {
            int l = wid * 32 + j * 16 + r15;
#pragma unroll
            for (int r = 0; r < 4; r++)
                f_low[(size_t)l * 8192 + b0 + q * 4 + r] = c[j][r] + bias_v[j];
        }
    } else {
        // transpose to [b][l] in LDS, then emit frag-major pf_img chunks
#pragma unroll
        for (int j = 0; j < 2; j++) {
            int l = wid * 32 + j * 16 + r15;
#pragma unroll
            for (int r = 0; r < 4; r++)
                Tr[(q * 4 + r) * 136 + l] = f2bf(c[j][r] + bias_v[j]);
        }
        __syncthreads();
        int ks2 = tid >> 6, ln = tid & 63;
        int b_loc = ln & 15, k0 = ks2 * 32 + (ln >> 4) * 8;
        uint4 tv = *(const uint4*)(Tr + b_loc * 136 + k0);
        *(uint4*)(pf_img + ((size_t)((b0 >> 4) * 4 + ks2)) * 512 + (size_t)ln * 8) = tv;
    }
}

// ---------------- K2a: h partials ----------------
// grid 2048 = sb(256 of 32 samples) x jg(8). block 256 (4 waves).
// j-group = 512 rows (16 l x 32 m). wave w: tiles w*8..w*8+8 (4 l's, both m-halves).
__global__ __launch_bounds__(256) void k2_h(
    const ushort* __restrict__ pg_img, const ushort* __restrict__ pf_img,
    const float* __restrict__ pg_b, const float* __restrict__ f_low,
    float* __restrict__ h_part /*[8][32][8192]*/)
{
    __shared__ __align__(16) float flow[16 * 32];
    __shared__ __align__(16) float biasl[512];
    __shared__ __align__(16) float hred[4 * 32 * 32];
    const int tid = threadIdx.x;
    const int lane = tid & 63, wid = tid >> 6;
    const int q = lane >> 4, r15 = lane & 15;
    const int jg = blockIdx.x & 7, sb = blockIdx.x >> 3;
    const int b0 = sb * 32;

    // B-frags for 32 samples (global, frag-major, wave-contiguous)
    bf16x8 bfr[2][4];
#pragma unroll
    for (int ct = 0; ct < 2; ct++)
#pragma unroll
        for (int ks = 0; ks < 4; ks++)
            bfr[ct][ks] = *(const bf16x8*)(pf_img + ((size_t)((sb * 2 + ct) * 4 + ks)) * 512 + lane * 8);

    if (tid < 128) {         // flow [16 l][32 b]
        int row = tid >> 3, c4 = (tid & 7) * 4;
        *(float4*)(flow + row * 32 + c4) =
            *(const float4*)(f_low + (size_t)(jg * 16 + row) * 8192 + b0 + c4);
    } else {                 // biases (512 f32)
        int t = tid - 128;
        *(float4*)(biasl + t * 4) = *(const float4*)(pg_b + jg * 512 + t * 4);
    }
    __syncthreads();

    f32x4 hacc[2][2];   // [m-half][ct]
#pragma unroll
    for (int i = 0; i < 2; i++)
#pragma unroll
        for (int j = 0; j < 2; j++) hacc[i][j] = (f32x4){0.f, 0.f, 0.f, 0.f};

    const ushort* Tbase = pg_img + (size_t)(jg * 32 + wid * 8) * 2048;
    bf16x8 af[2][4];
#pragma unroll
    for (int ks = 0; ks < 4; ks++) af[0][ks] = *(const bf16x8*)(Tbase + ks * 512 + lane * 8);
#pragma unroll
    for (int i = 0; i < 8; i++) {              // FULL unroll
        const int cur = i & 1, nxt = cur ^ 1;
        if (i < 7) {
#pragma unroll
            for (int ks = 0; ks < 4; ks++)
                af[nxt][ks] = *(const bf16x8*)(Tbase + (size_t)(i + 1) * 2048 + ks * 512 + lane * 8);
        }
        const int tl = wid * 8 + i;            // tile in group: l_loc = tl>>1, mh = tl&1
        const int l_loc = tl >> 1, mh = tl & 1;
        f32x4 bv = *(const f32x4*)(biasl + tl * 16 + q * 4);
#pragma unroll
        for (int ct = 0; ct < 2; ct++) {
            f32x4 cc = (f32x4){0.f, 0.f, 0.f, 0.f};
#pragma unroll
            for (int ks = 0; ks < 4; ks++) cc = MFMA(af[cur][ks], bfr[ct][ks], cc);
            float s = flow[l_loc * 32 + ct * 16 + r15];
#pragma unroll
            for (int r = 0; r < 4; r++) hacc[mh][ct][r] += s * (cc[r] + bv[r]);
        }
    }
    // cross-wave reduce via LDS
#pragma unroll
    for (int mh = 0; mh < 2; mh++)
#pragma unroll
        for (int ct = 0; ct < 2; ct++)
#pragma unroll
            for (int r = 0; r < 4; r++)
                hred[wid * 1024 + (mh * 16 + q * 4 + r) * 32 + ct * 16 + r15] = hacc[mh][ct][r];
    __syncthreads();
    {
        int m = tid >> 3, bq = (tid & 7) * 4;
        const float* h0 = hred + m * 32 + bq;
        float4 s;
        s.x = h0[0] + h0[1024] + h0[2048] + h0[3072];
        s.y = h0[1] + h0[1025] + h0[2049] + h0[3073];
        s.z = h0[2] + h0[1026] + h0[2050] + h0[3074];
        s.w = h0[3] + h0[1027] + h0[2051] + h0[3075];
        *(float4*)(h_part + (size_t)jg * 262144 + (size_t)m * 8192 + b0 + bq) = s;
    }
}

// ---------------- K2b: g (full m-reduction in block) ----------------
// grid 1024 = sb(256 of 32 samples) x lg(4 of 32 l). wave w: m in {w,w+4,..,w+28} x 2 lt.
__global__ __launch_bounds__(256) void k2_g(
    const ushort* __restrict__ pg_img, const ushort* __restrict__ pf_img,
    const float* __restrict__ pg_b, const float* __restrict__ h_part,
    ushort* __restrict__ g_img /*frag-major [512 bt][4 ks][64][8]*/)
{
    __shared__ __align__(16) float hl[32 * 32];
    __shared__ __align__(16) float biasl[32 * 32];
    __shared__ __align__(16) float gred[4 * 32 * 32];
    const int tid = threadIdx.x;
    const int lane = tid & 63, wid = tid >> 6;
    const int q = lane >> 4, r15 = lane & 15;
    const int lg = blockIdx.x & 3, sb = blockIdx.x >> 2;
    const int b0 = sb * 32;

    bf16x8 bfr[2][4];
#pragma unroll
    for (int ct = 0; ct < 2; ct++)
#pragma unroll
        for (int ks = 0; ks < 4; ks++)
            bfr[ct][ks] = *(const bf16x8*)(pf_img + ((size_t)((sb * 2 + ct) * 4 + ks)) * 512 + lane * 8);

    {   // hl = relu(sum_jg h_part)  [32 m][32 b]; biasl [32 m][32 l]
        int m = tid >> 3, c4 = (tid & 7) * 4;
        float4 s = (float4){0.f, 0.f, 0.f, 0.f};
#pragma unroll
        for (int g = 0; g < 8; g++) {
            float4 a = *(const float4*)(h_part + (size_t)g * 262144 + (size_t)m * 8192 + b0 + c4);
            s.x += a.x; s.y += a.y; s.z += a.z; s.w += a.w;
        }
        s.x = fmaxf(s.x, 0.f); s.y = fmaxf(s.y, 0.f); s.z = fmaxf(s.z, 0.f); s.w = fmaxf(s.w, 0.f);
        *(float4*)(hl + m * 32 + c4) = s;
        *(float4*)(biasl + m * 32 + c4) =
            *(const float4*)(pg_b + 4096 + (size_t)m * 128 + lg * 32 + c4);
    }
    __syncthreads();

    f32x4 gacc[2][2];   // [lt][ct]
#pragma unroll
    for (int i = 0; i < 2; i++)
#pragma unroll
        for (int j = 0; j < 2; j++) gacc[i][j] = (f32x4){0.f, 0.f, 0.f, 0.f};

    // tiles ti 0..15: mi = ti>>1, lt = ti&1, m = wid + 4*mi; T = 256 + m*8 + lg*2 + lt
    bf16x8 af[2][4];
#pragma unroll
    for (int ks = 0; ks < 4; ks++)
        af[0][ks] = *(const bf16x8*)(pg_img + (size_t)(256 + wid * 8 + lg * 2) * 2048 + ks * 512 + lane * 8);
#pragma unroll
    for (int ti = 0; ti < 16; ti++) {          // FULL unroll
        const int cur = ti & 1, nxt = cur ^ 1;
        if (ti < 15) {
            const int tn = ti + 1;
            const int mn = wid + 4 * (tn >> 1), ltn = tn & 1;
            const ushort* ap = pg_img + (size_t)(256 + mn * 8 + lg * 2 + ltn) * 2048;
#pragma unroll
            for (int ks = 0; ks < 4; ks++)
                af[nxt][ks] = *(const bf16x8*)(ap + ks * 512 + lane * 8);
        }
        const int m = wid + 4 * (ti >> 1), lt = ti & 1;
        f32x4 bv = *(const f32x4*)(biasl + m * 32 + lt * 16 + q * 4);
#pragma unroll
        for (int ct = 0; ct < 2; ct++) {
            f32x4 cc = (f32x4){0.f, 0.f, 0.f, 0.f};
#pragma unroll
            for (int ks = 0; ks < 4; ks++) cc = MFMA(af[cur][ks], bfr[ct][ks], cc);
            float s = hl[m * 32 + ct * 16 + r15];
#pragma unroll
            for (int r = 0; r < 4; r++) gacc[lt][ct][r] += s * (cc[r] + bv[r]);
        }
    }
    // cross-wave reduce -> g bf16 in frag-major layout
#pragma unroll
    for (int lt = 0; lt < 2; lt++)
#pragma unroll
        for (int ct = 0; ct < 2; ct++)
#pragma unroll
            for (int r = 0; r < 4; r++)
                gred[wid * 1024 + (lt * 16 + q * 4 + r) * 32 + ct * 16 + r15] = gacc[lt][ct][r];
    __syncthreads();
    if (tid < 128) {
        int bt = tid >> 6, ln = tid & 63;
        int b_loc = bt * 16 + (ln & 15);
        int l0 = (ln >> 4) * 8;
        ushort tmp[8];
#pragma unroll
        for (int e = 0; e < 8; e++) {
            const float* gp = gred + (l0 + e) * 32 + b_loc;
            tmp[e] = f2bf(gp[0] + gp[1024] + gp[2048] + gp[3072]);
        }
        ushort4 lo = {tmp[0], tmp[1], tmp[2], tmp[3]};
        ushort4 hi = {tmp[4], tmp[5], tmp[6], tmp[7]};
        ushort* dst = g_img + ((size_t)((sb * 2 + bt) * 4 + lg)) * 512 + (size_t)ln * 8;
        ((ushort4*)dst)[0] = lo;
        ((ushort4*)dst)[1] = hi;
    }
}

// ---------------- K3: out = g@W2^T + b2 + f + pf ----------------
// grid 512 = sb(128 of 64 samples) x nb(4 of 256 n). block 256.
// Two passes over 32-sample halves; LDS transpose (chunk stride 36 = conflict-free).
__global__ __launch_bounds__(256) void k3_out(
    const ushort* __restrict__ g_img, const ushort* __restrict__ w2_img,
    const float* __restrict__ b2, const float* __restrict__ f,
    const float* __restrict__ pf, float* __restrict__ out)
{
    __shared__ __align__(16) float Ls[32 * 288];   // 36.9 KB; 8 chunks x 36 words
    const int tid = threadIdx.x;
    const int lane = tid & 63, wid = tid >> 6;
    const int q = lane >> 4, r15 = lane & 15;
    const int sb = blockIdx.x >> 2, nb = blockIdx.x & 3;
    const int b0 = sb * 64, n0 = nb * 256;
    float bias_v[4];
#pragma unroll
    for (int nt = 0; nt < 4; nt++) bias_v[nt] = b2[n0 + wid * 64 + nt * 16 + r15];

#pragma unroll
    for (int p = 0; p < 2; p++) {
        bf16x8 af[2][4];
#pragma unroll
        for (int mtl = 0; mtl < 2; mtl++)
#pragma unroll
            for (int ks = 0; ks < 4; ks++)
                af[mtl][ks] = *(const bf16x8*)(g_img + ((size_t)((sb * 4 + p * 2 + mtl) * 4 + ks)) * 512 + lane * 8);
        bf16x8 wfr[2][4];
#pragma unroll
        for (int ks = 0; ks < 4; ks++)
            wfr[0][ks] = *(const bf16x8*)(w2_img + ((size_t)((nb * 16 + wid * 4) * 4 + ks)) * 512 + lane * 8);
#pragma unroll
        for (int nt = 0; nt < 4; nt++) {       // FULL unroll, ring-2
            const int cur = nt & 1, nxt = cur ^ 1;
            if (nt < 3) {
#pragma unroll
                for (int ks = 0; ks < 4; ks++)
                    wfr[nxt][ks] = *(const bf16x8*)(w2_img + ((size_t)((nb * 16 + wid * 4 + nt + 1) * 4 + ks)) * 512 + lane * 8);
            }
#pragma unroll
            for (int mtl = 0; mtl < 2; mtl++) {
                f32x4 cc = (f32x4){0.f, 0.f, 0.f, 0.f};
#pragma unroll
                for (int ks = 0; ks < 4; ks++) cc = MFMA(af[mtl][ks], wfr[cur][ks], cc);
                const int nloc = wid * 64 + nt * 16 + r15;        // 0..255
                const int chunk = nloc >> 5, within = nloc & 31;
#pragma unroll
                for (int r = 0; r < 4; r++)
                    Ls[(mtl * 16 + q * 4 + r) * 288 + chunk * 36 + within] = cc[r] + bias_v[nt];
            }
        }
        __syncthreads();
        {
            int b_loc = tid >> 3, ch = tid & 7;
            const size_t gbase = (size_t)(b0 + p * 32 + b_loc) * 1024 + n0 + ch * 32;
            const float* ls = Ls + b_loc * 288 + ch * 36;
#pragma unroll
            for (int i = 0; i < 8; i++) {
                float4 lv = *(const float4*)(ls + i * 4);
                float4 fa = *(const float4*)(f + gbase + i * 4);
                float4 pa = *(const float4*)(pf + gbase + i * 4);
                float4 o;
                o.x = lv.x + fa.x + pa.x; o.y = lv.y + fa.y + pa.y;
                o.z = lv.z + fa.z + pa.z; o.w = lv.w + fa.w + pa.w;
                *(float4*)(out + gbase + i * 4) = o;
            }
        }
        __syncthreads();
    }
}

// ---------------- launch ----------------
extern "C" void kernel_launch(void* const* d_in, const int* in_sizes, int n_in,
                              void* d_out, int out_size, void* d_ws, size_t ws_size,
                              hipStream_t stream)
{
    const float* f    = (const float*)d_in[0];
    const float* pf   = (const float*)d_in[1];
    const float* wf   = (const float*)d_in[2];
    const float* bfb  = (const float*)d_in[3];
    const float* wpf  = (const float*)d_in[4];
    const float* bpfb = (const float*)d_in[5];
    const float* w2   = (const float*)d_in[6];
    const float* b2   = (const float*)d_in[7];
    const float* pgw  = (const float*)d_in[8];
    const float* pgb  = (const float*)d_in[9];

    char* ws = (char*)d_ws;
    ushort* pg_img = (ushort*)(ws + 0);          // 2 MB
    ushort* w_img  = (ushort*)(ws + 2097152);    // 512 KB
    ushort* w2_img = (ushort*)(ws + 2621440);    // 256 KB
    float*  f_low  = (float*)(ws + 2883584);     // 4 MB  [128 l][8192 b]
    ushort* pf_img = (ushort*)(ws + 7077888);    // 2 MB  frag-major
    float*  h_part = (float*)(ws + 9175040);     // 8 MB  [8][32][8192]
    ushort* g_img  = (ushort*)(ws + 17563648);   // 2 MB  frag-major
    float*  out    = (float*)d_out;

    k0_convert<<<dim3(704), dim3(256), 0, stream>>>(pgw, wf, wpf, w2, pg_img, w_img, w2_img);
    k1_proj<<<dim3(1024), dim3(256), 0, stream>>>(f, pf, w_img, bfb, bpfb, f_low, pf_img);
    k2_h<<<dim3(2048), dim3(256), 0, stream>>>(pg_img, pf_img, pgb, f_low, h_part);
    k2_g<<<dim3(1024), dim3(256), 0, stream>>>(pg_img, pf_img, pgb, h_part, g_img);
    k3_out<<<dim3(512), dim3(256), 0, stream>>>(g_img, w2_img, b2, f, pf, out);
}

// Round 5
// 180.511 us; speedup vs baseline: 1.6768x; 1.1445x over previous
//
#include <hip/hip_runtime.h>
#include <hip/hip_bf16.h>
#include <stdint.h>

// DynamicFc R5: R4 + two fixes:
//  (1) __launch_bounds__(256, 4) on all MFMA kernels. R4's (256) let the
//      compiler target 8 waves/EU (~64 VGPR) and demote fragment arrays to
//      scratch (k3: VGPR_Count=52 < 64 static frag regs; WRITE_SIZE 57MB vs
//      32 ideal). (256,4) = 128-VGPR budget >= ~90-110 static need; LDS caps
//      blocks/CU at 4 anyway so no occupancy loss.
//  (2) k3 restructured: 32-sample blocks (grid 1024), epilogue fully
//      wave-contiguous (lane i <-> n0+4i; 1KB/instr for f/pf/out).
// B=8192, F=1024, LOW=128, MID=32. p1: j=l*32+m (j<4096), p2: j=4096+m*128+l.
// Fragment-major images: chunk(T,ks)[lane][8] = W[T*16+(lane&15)][ks*32+(lane>>4)*8..+8]

typedef __attribute__((ext_vector_type(8))) short bf16x8;
typedef __attribute__((ext_vector_type(4))) float f32x4;

#define MFMA(a, b, c) __builtin_amdgcn_mfma_f32_16x16x32_bf16((a), (b), (c), 0, 0, 0)

__device__ __forceinline__ ushort f2bf(float x) {
    union { float f; uint32_t u; } v; v.f = x;
    return (ushort)((v.u + 0x7FFFu + ((v.u >> 16) & 1u)) >> 16);
}
__device__ __forceinline__ ushort4 f2bf4(float4 v) {
    ushort4 o; o.x = f2bf(v.x); o.y = f2bf(v.y); o.z = f2bf(v.z); o.w = f2bf(v.w); return o;
}

// ---------------- K0: convert + fragment-major re-layout ----------------
__global__ __launch_bounds__(256) void k0_convert(
    const float* __restrict__ pgw, const float* __restrict__ wf,
    const float* __restrict__ wpf, const float* __restrict__ w2,
    ushort* __restrict__ pg_img, ushort* __restrict__ w_img, ushort* __restrict__ w2_img)
{
    int cid = blockIdx.x * 256 + threadIdx.x;   // 704*256 = 180224
    const float* src; ushort* dst;
    if (cid < 131072) {                                  // pg: 512*4*64
        int lane = cid & 63, ks = (cid >> 6) & 3, T = cid >> 8;
        int j = T * 16 + (lane & 15), k = ks * 32 + (lane >> 4) * 8;
        src = pgw + (size_t)j * 128 + k;
        dst = pg_img + (size_t)cid * 8;
    } else if (cid < 163840) {                           // wf/wpf: 2*8*32*64
        int c = cid - 131072;
        int lane = c & 63, ks = (c >> 6) & 31, lt = (c >> 11) & 7, mat = c >> 14;
        int l = lt * 16 + (lane & 15), k = ks * 32 + (lane >> 4) * 8;
        src = (mat ? wpf : wf) + (size_t)l * 1024 + k;
        dst = w_img + (size_t)c * 8;
    } else {                                             // w2: 64*4*64
        int c = cid - 163840;
        int lane = c & 63, ks = (c >> 6) & 3, nt = c >> 8;
        int n = nt * 16 + (lane & 15), k = ks * 32 + (lane >> 4) * 8;
        src = w2 + (size_t)n * 128 + k;
        dst = w2_img + (size_t)c * 8;
    }
    float4 a = ((const float4*)src)[0], b = ((const float4*)src)[1];
    ((ushort4*)dst)[0] = f2bf4(a);
    ((ushort4*)dst)[1] = f2bf4(b);
}

// ---------------- K1: input projections ----------------
// grid 1024 = sb(512 of 16 samples) x mat(2). block 256 (4 waves).
__global__ __launch_bounds__(256, 4) void k1_proj(
    const float* __restrict__ f, const float* __restrict__ pf,
    const ushort* __restrict__ w_img,
    const float* __restrict__ bf_bias, const float* __restrict__ bpf_bias,
    float* __restrict__ f_low /*[l][b] f32*/, ushort* __restrict__ pf_img /*frag-major*/)
{
    __shared__ __align__(16) ushort As[16 * 1032];
    __shared__ __align__(16) ushort Tr[16 * 136];
    const int tid = threadIdx.x;
    const int lane = tid & 63, wid = tid >> 6;
    const int q = lane >> 4, r15 = lane & 15;
    const int mat = blockIdx.x & 1;
    const int b0 = (blockIdx.x >> 1) * 16;
    const float* src = mat ? pf : f;
    const float* bias_ptr = mat ? bpf_bias : bf_bias;

#pragma unroll
    for (int ch = 0; ch < 2; ch++) {
        float4 v[8];
#pragma unroll
        for (int rr = 0; rr < 8; rr++)
            v[rr] = *(const float4*)(src + (size_t)(b0 + ch * 8 + rr) * 1024 + tid * 4);
#pragma unroll
        for (int rr = 0; rr < 8; rr++)
            *(ushort4*)(As + (ch * 8 + rr) * 1032 + tid * 4) = f2bf4(v[rr]);
    }
    float bias_v[2];
#pragma unroll
    for (int j = 0; j < 2; j++) bias_v[j] = bias_ptr[wid * 32 + j * 16 + r15];
    __syncthreads();

    const int lt0 = wid * 2;
    const ushort* wb = w_img + (size_t)mat * 131072;
    bf16x8 wfr[4][2];
#pragma unroll
    for (int pre = 0; pre < 4; pre++)
#pragma unroll
        for (int j = 0; j < 2; j++)
            wfr[pre][j] = *(const bf16x8*)(wb + ((size_t)(lt0 + j) * 32 + pre) * 512 + lane * 8);

    f32x4 c[2];
    c[0] = (f32x4){0.f, 0.f, 0.f, 0.f};
    c[1] = (f32x4){0.f, 0.f, 0.f, 0.f};
#pragma unroll
    for (int ks = 0; ks < 32; ks++) {          // FULL unroll -> static ring indices
        const int cur = ks & 3;
        bf16x8 af = *(const bf16x8*)(As + r15 * 1032 + ks * 32 + q * 8);
        c[0] = MFMA(af, wfr[cur][0], c[0]);
        c[1] = MFMA(af, wfr[cur][1], c[1]);
        if (ks + 4 < 32) {
#pragma unroll
            for (int j = 0; j < 2; j++)
                wfr[cur][j] = *(const bf16x8*)(wb + ((size_t)(lt0 + j) * 32 + (ks + 4)) * 512 + lane * 8);
        }
    }
    // C: row = b_local (q*4+r), col = l (wid*32 + j*16 + r15)
    if (mat == 0) {
#pragma unroll
        for (int j = 0; j < 2; j++) {
            int l = wid * 32 + j * 16 + r15;
#pragma unroll
            for (int r = 0; r < 4; r++)
                f_low[(size_t)l * 8192 + b0 + q * 4 + r] = c[j][r] + bias_v[j];
        }
    } else {
        // transpose to [b][l] in LDS, then emit frag-major pf_img chunks
#pragma unroll
        for (int j = 0; j < 2; j++) {
            int l = wid * 32 + j * 16 + r15;
#pragma unroll
            for (int r = 0; r < 4; r++)
                Tr[(q * 4 + r) * 136 + l] = f2bf(c[j][r] + bias_v[j]);
        }
        __syncthreads();
        int ks2 = tid >> 6, ln = tid & 63;
        int b_loc = ln & 15, k0 = ks2 * 32 + (ln >> 4) * 8;
        uint4 tv = *(const uint4*)(Tr + b_loc * 136 + k0);
        *(uint4*)(pf_img + ((size_t)((b0 >> 4) * 4 + ks2)) * 512 + (size_t)ln * 8) = tv;
    }
}

// ---------------- K2a: h partials ----------------
// grid 2048 = sb(256 of 32 samples) x jg(8). block 256 (4 waves).
__global__ __launch_bounds__(256, 4) void k2_h(
    const ushort* __restrict__ pg_img, const ushort* __restrict__ pf_img,
    const float* __restrict__ pg_b, const float* __restrict__ f_low,
    float* __restrict__ h_part /*[8][32][8192]*/)
{
    __shared__ __align__(16) float flow[16 * 32];
    __shared__ __align__(16) float biasl[512];
    __shared__ __align__(16) float hred[4 * 32 * 32];
    const int tid = threadIdx.x;
    const int lane = tid & 63, wid = tid >> 6;
    const int q = lane >> 4, r15 = lane & 15;
    const int jg = blockIdx.x & 7, sb = blockIdx.x >> 3;
    const int b0 = sb * 32;

    bf16x8 bfr[2][4];
#pragma unroll
    for (int ct = 0; ct < 2; ct++)
#pragma unroll
        for (int ks = 0; ks < 4; ks++)
            bfr[ct][ks] = *(const bf16x8*)(pf_img + ((size_t)((sb * 2 + ct) * 4 + ks)) * 512 + lane * 8);

    if (tid < 128) {         // flow [16 l][32 b]
        int row = tid >> 3, c4 = (tid & 7) * 4;
        *(float4*)(flow + row * 32 + c4) =
            *(const float4*)(f_low + (size_t)(jg * 16 + row) * 8192 + b0 + c4);
    } else {                 // biases (512 f32)
        int t = tid - 128;
        *(float4*)(biasl + t * 4) = *(const float4*)(pg_b + jg * 512 + t * 4);
    }
    __syncthreads();

    f32x4 hacc[2][2];   // [m-half][ct]
#pragma unroll
    for (int i = 0; i < 2; i++)
#pragma unroll
        for (int j = 0; j < 2; j++) hacc[i][j] = (f32x4){0.f, 0.f, 0.f, 0.f};

    const ushort* Tbase = pg_img + (size_t)(jg * 32 + wid * 8) * 2048;
    bf16x8 af[2][4];
#pragma unroll
    for (int ks = 0; ks < 4; ks++) af[0][ks] = *(const bf16x8*)(Tbase + ks * 512 + lane * 8);
#pragma unroll
    for (int i = 0; i < 8; i++) {              // FULL unroll -> static ring indices
        const int cur = i & 1, nxt = cur ^ 1;
        if (i < 7) {
#pragma unroll
            for (int ks = 0; ks < 4; ks++)
                af[nxt][ks] = *(const bf16x8*)(Tbase + (size_t)(i + 1) * 2048 + ks * 512 + lane * 8);
        }
        const int tl = wid * 8 + i;
        const int l_loc = tl >> 1, mh = tl & 1;
        f32x4 bv = *(const f32x4*)(biasl + tl * 16 + q * 4);
#pragma unroll
        for (int ct = 0; ct < 2; ct++) {
            f32x4 cc = (f32x4){0.f, 0.f, 0.f, 0.f};
#pragma unroll
            for (int ks = 0; ks < 4; ks++) cc = MFMA(af[cur][ks], bfr[ct][ks], cc);
            float s = flow[l_loc * 32 + ct * 16 + r15];
#pragma unroll
            for (int r = 0; r < 4; r++) hacc[mh][ct][r] += s * (cc[r] + bv[r]);
        }
    }
#pragma unroll
    for (int mh = 0; mh < 2; mh++)
#pragma unroll
        for (int ct = 0; ct < 2; ct++)
#pragma unroll
            for (int r = 0; r < 4; r++)
                hred[wid * 1024 + (mh * 16 + q * 4 + r) * 32 + ct * 16 + r15] = hacc[mh][ct][r];
    __syncthreads();
    {
        int m = tid >> 3, bq = (tid & 7) * 4;
        const float* h0 = hred + m * 32 + bq;
        float4 s;
        s.x = h0[0] + h0[1024] + h0[2048] + h0[3072];
        s.y = h0[1] + h0[1025] + h0[2049] + h0[3073];
        s.z = h0[2] + h0[1026] + h0[2050] + h0[3074];
        s.w = h0[3] + h0[1027] + h0[2051] + h0[3075];
        *(float4*)(h_part + (size_t)jg * 262144 + (size_t)m * 8192 + b0 + bq) = s;
    }
}

// ---------------- K2b: g (full m-reduction in block) ----------------
// grid 1024 = sb(256 of 32 samples) x lg(4 of 32 l).
__global__ __launch_bounds__(256, 4) void k2_g(
    const ushort* __restrict__ pg_img, const ushort* __restrict__ pf_img,
    const float* __restrict__ pg_b, const float* __restrict__ h_part,
    ushort* __restrict__ g_img /*frag-major [512 bt][4 ks][64][8]*/)
{
    __shared__ __align__(16) float hl[32 * 32];
    __shared__ __align__(16) float biasl[32 * 32];
    __shared__ __align__(16) float gred[4 * 32 * 32];
    const int tid = threadIdx.x;
    const int lane = tid & 63, wid = tid >> 6;
    const int q = lane >> 4, r15 = lane & 15;
    const int lg = blockIdx.x & 3, sb = blockIdx.x >> 2;
    const int b0 = sb * 32;

    bf16x8 bfr[2][4];
#pragma unroll
    for (int ct = 0; ct < 2; ct++)
#pragma unroll
        for (int ks = 0; ks < 4; ks++)
            bfr[ct][ks] = *(const bf16x8*)(pf_img + ((size_t)((sb * 2 + ct) * 4 + ks)) * 512 + lane * 8);

    {   // hl = relu(sum_jg h_part)  [32 m][32 b]; biasl [32 m][32 l]
        int m = tid >> 3, c4 = (tid & 7) * 4;
        float4 s = (float4){0.f, 0.f, 0.f, 0.f};
#pragma unroll
        for (int g = 0; g < 8; g++) {
            float4 a = *(const float4*)(h_part + (size_t)g * 262144 + (size_t)m * 8192 + b0 + c4);
            s.x += a.x; s.y += a.y; s.z += a.z; s.w += a.w;
        }
        s.x = fmaxf(s.x, 0.f); s.y = fmaxf(s.y, 0.f); s.z = fmaxf(s.z, 0.f); s.w = fmaxf(s.w, 0.f);
        *(float4*)(hl + m * 32 + c4) = s;
        *(float4*)(biasl + m * 32 + c4) =
            *(const float4*)(pg_b + 4096 + (size_t)m * 128 + lg * 32 + c4);
    }
    __syncthreads();

    f32x4 gacc[2][2];   // [lt][ct]
#pragma unroll
    for (int i = 0; i < 2; i++)
#pragma unroll
        for (int j = 0; j < 2; j++) gacc[i][j] = (f32x4){0.f, 0.f, 0.f, 0.f};

    bf16x8 af[2][4];
#pragma unroll
    for (int ks = 0; ks < 4; ks++)
        af[0][ks] = *(const bf16x8*)(pg_img + (size_t)(256 + wid * 8 + lg * 2) * 2048 + ks * 512 + lane * 8);
#pragma unroll
    for (int ti = 0; ti < 16; ti++) {          // FULL unroll -> static ring indices
        const int cur = ti & 1, nxt = cur ^ 1;
        if (ti < 15) {
            const int tn = ti + 1;
            const int mn = wid + 4 * (tn >> 1), ltn = tn & 1;
            const ushort* ap = pg_img + (size_t)(256 + mn * 8 + lg * 2 + ltn) * 2048;
#pragma unroll
            for (int ks = 0; ks < 4; ks++)
                af[nxt][ks] = *(const bf16x8*)(ap + ks * 512 + lane * 8);
        }
        const int m = wid + 4 * (ti >> 1), lt = ti & 1;
        f32x4 bv = *(const f32x4*)(biasl + m * 32 + lt * 16 + q * 4);
#pragma unroll
        for (int ct = 0; ct < 2; ct++) {
            f32x4 cc = (f32x4){0.f, 0.f, 0.f, 0.f};
#pragma unroll
            for (int ks = 0; ks < 4; ks++) cc = MFMA(af[cur][ks], bfr[ct][ks], cc);
            float s = hl[m * 32 + ct * 16 + r15];
#pragma unroll
            for (int r = 0; r < 4; r++) gacc[lt][ct][r] += s * (cc[r] + bv[r]);
        }
    }
#pragma unroll
    for (int lt = 0; lt < 2; lt++)
#pragma unroll
        for (int ct = 0; ct < 2; ct++)
#pragma unroll
            for (int r = 0; r < 4; r++)
                gred[wid * 1024 + (lt * 16 + q * 4 + r) * 32 + ct * 16 + r15] = gacc[lt][ct][r];
    __syncthreads();
    if (tid < 128) {
        int bt = tid >> 6, ln = tid & 63;
        int b_loc = bt * 16 + (ln & 15);
        int l0 = (ln >> 4) * 8;
        ushort tmp[8];
#pragma unroll
        for (int e = 0; e < 8; e++) {
            const float* gp = gred + (l0 + e) * 32 + b_loc;
            tmp[e] = f2bf(gp[0] + gp[1024] + gp[2048] + gp[3072]);
        }
        ushort4 lo = {tmp[0], tmp[1], tmp[2], tmp[3]};
        ushort4 hi = {tmp[4], tmp[5], tmp[6], tmp[7]};
        ushort* dst = g_img + ((size_t)((sb * 2 + bt) * 4 + lg)) * 512 + (size_t)ln * 8;
        ((ushort4*)dst)[0] = lo;
        ((ushort4*)dst)[1] = hi;
    }
}

// ---------------- K3: out = g@W2^T + b2 + f + pf ----------------
// grid 1024 = sb(256 of 32 samples) x nb(4 of 256 n). block 256 (4 waves).
// MFMA phase -> LDS (chunk stride 36, conflict-free) -> wave-contiguous epilogue
// (lane i <-> n0+4i: every f/pf load and out store is 1KB contiguous per instr).
__global__ __launch_bounds__(256, 4) void k3_out(
    const ushort* __restrict__ g_img, const ushort* __restrict__ w2_img,
    const float* __restrict__ b2, const float* __restrict__ f,
    const float* __restrict__ pf, float* __restrict__ out)
{
    __shared__ __align__(16) float Ls[32 * 288];   // 36864 B
    const int tid = threadIdx.x;
    const int lane = tid & 63, wid = tid >> 6;
    const int q = lane >> 4, r15 = lane & 15;
    const int sb = blockIdx.x >> 2, nb = blockIdx.x & 3;
    const int b0 = sb * 32, n0 = nb * 256;

    float bias_v[4];
#pragma unroll
    for (int nt = 0; nt < 4; nt++) bias_v[nt] = b2[n0 + wid * 64 + nt * 16 + r15];

    bf16x8 af[2][4];
#pragma unroll
    for (int mtl = 0; mtl < 2; mtl++)
#pragma unroll
        for (int ks = 0; ks < 4; ks++)
            af[mtl][ks] = *(const bf16x8*)(g_img + ((size_t)((sb * 2 + mtl) * 4 + ks)) * 512 + lane * 8);
    bf16x8 wfr[2][4];
#pragma unroll
    for (int ks = 0; ks < 4; ks++)
        wfr[0][ks] = *(const bf16x8*)(w2_img + ((size_t)((nb * 16 + wid * 4) * 4 + ks)) * 512 + lane * 8);
#pragma unroll
    for (int nt = 0; nt < 4; nt++) {           // FULL unroll, ring-2
        const int cur = nt & 1, nxt = cur ^ 1;
        if (nt < 3) {
#pragma unroll
            for (int ks = 0; ks < 4; ks++)
                wfr[nxt][ks] = *(const bf16x8*)(w2_img + ((size_t)((nb * 16 + wid * 4 + nt + 1) * 4 + ks)) * 512 + lane * 8);
        }
#pragma unroll
        for (int mtl = 0; mtl < 2; mtl++) {
            f32x4 cc = (f32x4){0.f, 0.f, 0.f, 0.f};
#pragma unroll
            for (int ks = 0; ks < 4; ks++) cc = MFMA(af[mtl][ks], wfr[cur][ks], cc);
            const int nloc = wid * 64 + nt * 16 + r15;        // 0..255
            const int chunk = nloc >> 5, within = nloc & 31;
#pragma unroll
            for (int r = 0; r < 4; r++)
                Ls[(mtl * 16 + q * 4 + r) * 288 + chunk * 36 + within] = cc[r] + bias_v[nt];
        }
    }
    __syncthreads();
    // epilogue: wave w handles rows w*8..w*8+8; lane i covers n0+4i..+4 (contiguous)
    {
        const float* ls = Ls + (wid * 8) * 288 + (lane >> 3) * 36 + (lane & 7) * 4;
#pragma unroll
        for (int rr = 0; rr < 8; rr++) {
            const int b = b0 + wid * 8 + rr;
            const size_t gbase = (size_t)b * 1024 + n0 + lane * 4;
            float4 lv = *(const float4*)(ls + rr * 288);
            float4 fa = *(const float4*)(f + gbase);
            float4 pa = *(const float4*)(pf + gbase);
            float4 o;
            o.x = lv.x + fa.x + pa.x; o.y = lv.y + fa.y + pa.y;
            o.z = lv.z + fa.z + pa.z; o.w = lv.w + fa.w + pa.w;
            *(float4*)(out + gbase) = o;
        }
    }
}

// ---------------- launch ----------------
extern "C" void kernel_launch(void* const* d_in, const int* in_sizes, int n_in,
                              void* d_out, int out_size, void* d_ws, size_t ws_size,
                              hipStream_t stream)
{
    const float* f    = (const float*)d_in[0];
    const float* pf   = (const float*)d_in[1];
    const float* wf   = (const float*)d_in[2];
    const float* bfb  = (const float*)d_in[3];
    const float* wpf  = (const float*)d_in[4];
    const float* bpfb = (const float*)d_in[5];
    const float* w2   = (const float*)d_in[6];
    const float* b2   = (const float*)d_in[7];
    const float* pgw  = (const float*)d_in[8];
    const float* pgb  = (const float*)d_in[9];

    char* ws = (char*)d_ws;
    ushort* pg_img = (ushort*)(ws + 0);          // 2 MB
    ushort* w_img  = (ushort*)(ws + 2097152);    // 512 KB
    ushort* w2_img = (ushort*)(ws + 2621440);    // 256 KB
    float*  f_low  = (float*)(ws + 2883584);     // 4 MB  [128 l][8192 b]
    ushort* pf_img = (ushort*)(ws + 7077888);    // 2 MB  frag-major
    float*  h_part = (float*)(ws + 9175040);     // 8 MB  [8][32][8192]
    ushort* g_img  = (ushort*)(ws + 17563648);   // 2 MB  frag-major
    float*  out    = (float*)d_out;

    k0_convert<<<dim3(704), dim3(256), 0, stream>>>(pgw, wf, wpf, w2, pg_img, w_img, w2_img);
    k1_proj<<<dim3(1024), dim3(256), 0, stream>>>(f, pf, w_img, bfb, bpfb, f_low, pf_img);
    k2_h<<<dim3(2048), dim3(256), 0, stream>>>(pg_img, pf_img, pgb, f_low, h_part);
    k2_g<<<dim3(1024), dim3(256), 0, stream>>>(pg_img, pf_img, pgb, h_part, g_img);
    k3_out<<<dim3(1024), dim3(256), 0, stream>>>(g_img, w2_img, b2, f, pf, out);
}